// Round 12
// baseline (1495.890 us; speedup 1.0000x reference)
//
#include <hip/hip_runtime.h>
#include <hip/hip_bf16.h>
#include <math.h>

#define BB 8
#define WW 256
#define FF 16
#define DD 128
#define HH 8
#define NTOK (BB*WW*FF)        // 32768
#define QSCALE 0.12751745f     // DH^-0.5 * log2(e)  (softmax uses exp2)
#define INV_D (1.0f/128.0f)
#define LN10K_D 0.07195578415606394f   // ln(10000)/128

typedef __hip_bfloat16 bf16;
typedef short bf16x8 __attribute__((ext_vector_type(8)));   // 8 bf16 = 4 VGPRs
typedef float f32x4 __attribute__((ext_vector_type(4)));

__device__ __forceinline__ float bf2f(bf16 x){ return __bfloat162float(x); }
__device__ __forceinline__ bf16 f2bf(float x){ return __float2bfloat16(x); }
__device__ __forceinline__ unsigned short bfbits(float x){ bf16 b = f2bf(x); return *(unsigned short*)&b; }
__device__ __forceinline__ float bits2f(unsigned short u){ bf16 b = *(bf16*)&u; return __bfloat162float(b); }

#define MFMA16 __builtin_amdgcn_mfma_f32_16x16x32_bf16

// k/v layout: [bl][f][h][w][d] (w,d contiguous per (b,f,h): 64 KB slice).
// q/ot: token-major [tok][h*128+d].

// ---------------------------------------------------------------------------
// MERGED prep: blocks 0..543 = weight transpose+convert; 544.. = embed(+LN0).
// ---------------------------------------------------------------------------
__global__ __launch_bounds__(256) void prep_kernel(
    const float* __restrict__ wqkv, const float* __restrict__ wout,
    const float* __restrict__ wh,
    bf16* __restrict__ wqkvT, bf16* __restrict__ woutT, bf16* __restrict__ whT,
    const float* __restrict__ x,
    const float* __restrict__ w1, const float* __restrict__ b1,
    const float* __restrict__ w2, const float* __restrict__ b2,
    const float* __restrict__ w3, const float* __restrict__ b3,
    const float* __restrict__ wval, const float* __restrict__ bval,
    const float* __restrict__ g, const float* __restrict__ bln,
    float* __restrict__ h, bf16* __restrict__ hn)
{
    __shared__ __align__(16) char smem[16640];
    int tid = threadIdx.x;

    if (blockIdx.x < 544) {
        float (*tile)[65] = (float(*)[65])smem;
        int bx = blockIdx.x;
        const float* in; bf16* outp; int r0, c0, sin, sout, nmax;
        if (bx < 384) {
            int l = bx / 96, t = bx % 96;
            r0 = (t / 48)*64; c0 = (t % 48)*64;
            in = wqkv + (size_t)l*128*3072; outp = wqkvT + (size_t)l*3072*128;
            sin = 3072; sout = 128; nmax = 3072;
        } else if (bx < 512) {
            int j = bx - 384, l = j / 32, t = j % 32;
            r0 = (t / 2)*64; c0 = (t % 2)*64;
            in = wout + (size_t)l*1024*128; outp = woutT + (size_t)l*128*1024;
            sin = 128; sout = 1024; nmax = 128;
        } else {
            int t = bx - 512;
            r0 = t*64; c0 = 0;
            in = wh; outp = whT; sin = 16; sout = 2048; nmax = 16;
        }
        int rr = tid >> 2, cg = (tid & 3)*16;
        if (c0 + cg < nmax) {
            const float* src = in + (size_t)(r0 + rr)*sin + c0 + cg;
            #pragma unroll
            for (int i = 0; i < 4; i++)
                *(float4*)&tile[rr][cg + i*4] = *(const float4*)(src + i*4);
        }
        __syncthreads();
        int n = c0 + rr;
        if (n < nmax) {
            union { uint4 u[2]; unsigned short sh[16]; } o;
            #pragma unroll
            for (int e = 0; e < 16; e++) o.sh[e] = bfbits(tile[cg + e][rr]);
            bf16* dst = outp + (size_t)n*sout + r0 + cg;
            *(uint4*)dst = o.u[0];
            *(uint4*)(dst + 8) = o.u[1];
        }
        return;
    }

    float (*s)[4] = (float(*)[4])smem;
    float* hs = (float*)(smem + 256);
    int bw = blockIdx.x - 544;
    int b = bw >> 8, w = bw & 255;
    if (tid < 64) {
        int f = tid >> 2, t = tid & 3;
        const float* xb = x + (size_t)b*WW*FF + f;
        float v;
        if (t == 0) {
            v = xb[(size_t)w*FF];
        } else if (t == 1) {
            float acc = b1[f];
            #pragma unroll
            for (int kk = 0; kk < 4; kk++) { int t0 = w - (3-kk); if (t0 >= 0) acc += w1[f*4+kk]*xb[(size_t)t0*FF]; }
            v = acc;
        } else if (t == 2) {
            float acc = b2[f];
            #pragma unroll
            for (int kk = 0; kk < 8; kk++) { int t0 = w - (7-kk)*2; if (t0 >= 0) acc += w2[f*8+kk]*xb[(size_t)t0*FF]; }
            v = acc;
        } else {
            float acc = b3[f];
            #pragma unroll
            for (int kk = 0; kk < 16; kk++) { int t0 = w - (15-kk)*3; if (t0 >= 0) acc += w3[f*16+kk]*xb[(size_t)t0*FF]; }
            v = acc;
        }
        s[f][t] = v;
    }
    __syncthreads();
    #pragma unroll
    for (int r = 0; r < 8; r++) {
        int lin = r*256 + tid;
        int f = lin >> 7, d = lin & 127;
        float div = expf(-(float)(d & ~1) * LN10K_D);
        float arg = (float)w * div;
        float pe = (d & 1) ? cosf(arg) : sinf(arg);
        float e = bval[d] + pe;
        #pragma unroll
        for (int t = 0; t < 4; t++) e += s[f][t]*wval[t*128 + d];
        h[((size_t)bw*FF + f)*128 + d] = e;
        hs[f*132 + d] = e;
    }
    __syncthreads();
    int tok = tid >> 4, sub = tid & 15;
    float xv[8];
    #pragma unroll
    for (int e2 = 0; e2 < 8; e2++) xv[e2] = hs[tok*132 + sub*8 + e2];
    float s1 = 0.f, s2 = 0.f;
    #pragma unroll
    for (int e2 = 0; e2 < 8; e2++) { s1 += xv[e2]; s2 += xv[e2]*xv[e2]; }
    #pragma unroll
    for (int m = 1; m < 16; m <<= 1) { s1 += __shfl_xor(s1, m, 64); s2 += __shfl_xor(s2, m, 64); }
    float mean = s1*INV_D;
    float var  = s2*INV_D - mean*mean;
    float rs = rsqrtf(var + 1e-5f);
    union { uint4 u; unsigned short sh[8]; } ou;
    #pragma unroll
    for (int e2 = 0; e2 < 8; e2++) {
        int d = sub*8 + e2;
        ou.sh[e2] = bfbits((xv[e2]-mean)*rs*g[d] + bln[d]);
    }
    *(uint4*)(hn + ((size_t)bw*16 + tok)*128 + sub*8) = ou.u;
}

// ---------------------------------------------------------------------------
// QKV GEMM, MFMA.  q -> token-major (scaled by QSCALE); k/v -> [bl][f][h][w][d].
// ---------------------------------------------------------------------------
__global__ __launch_bounds__(256) void qkv_mfma(
    const bf16* __restrict__ hn, const bf16* __restrict__ wT,
    bf16* __restrict__ q, bf16* __restrict__ k, bf16* __restrict__ v)
{
    __shared__ __align__(16) unsigned short Cs[4][64][72];   // 36,864 B
    int tid = threadIdx.x;
    int lane = tid & 63, wave = tid >> 6;
    int quad = lane >> 4, l16 = lane & 15;
    int wm = wave >> 1, wn = wave & 1;
    int m0 = blockIdx.x * 128, n0 = blockIdx.y * 128;

    f32x4 acc[4][4];
    #pragma unroll
    for (int a = 0; a < 4; a++)
        #pragma unroll
        for (int c = 0; c < 4; c++) acc[a][c] = 0.f;

    #pragma unroll
    for (int kt = 0; kt < 4; kt++) {
        int ko = kt*32 + quad*8;
        bf16x8 af[4], bfr[4];
        #pragma unroll
        for (int tm = 0; tm < 4; tm++)
            af[tm] = *(const bf16x8*)(hn + (size_t)(m0 + wm*64 + tm*16 + l16)*128 + ko);
        #pragma unroll
        for (int tn = 0; tn < 4; tn++)
            bfr[tn] = *(const bf16x8*)(wT + (size_t)(n0 + wn*64 + tn*16 + l16)*128 + ko);
        #pragma unroll
        for (int tm = 0; tm < 4; tm++)
            #pragma unroll
            for (int tn = 0; tn < 4; tn++)
                acc[tm][tn] = MFMA16(af[tm], bfr[tn], acc[tm][tn], 0, 0, 0);
    }

    bf16* dst; int nrel; float scl; int isq;
    if (n0 < 1024)      { dst = q; nrel = n0;        scl = QSCALE; isq = 1; }
    else if (n0 < 2048) { dst = k; nrel = n0 - 1024; scl = 1.0f;   isq = 0; }
    else                { dst = v; nrel = n0 - 2048; scl = 1.0f;   isq = 0; }

    #pragma unroll
    for (int tm = 0; tm < 4; tm++)
        #pragma unroll
        for (int tn = 0; tn < 4; tn++)
            #pragma unroll
            for (int r = 0; r < 4; r++)
                Cs[wave][tm*16 + quad*4 + r][tn*16 + l16] = bfbits(acc[tm][tn][r]*scl);

    if (isq) {
        #pragma unroll
        for (int p = 0; p < 8; p++) {
            int row = p*8 + (lane >> 3);
            int c8  = (lane & 7)*8;
            uint4 val = *(const uint4*)&Cs[wave][row][c8];
            size_t gaddr = (size_t)(m0 + wm*64 + row)*1024 + nrel + wn*64 + c8;
            *(uint4*)(dst + gaddr) = val;
        }
    } else {
        int hh = nrel >> 7;
        #pragma unroll
        for (int p = 0; p < 8; p++) {
            int row = p*8 + (lane >> 3);
            int c8  = (lane & 7)*8;
            uint4 val = *(const uint4*)&Cs[wave][row][c8];
            int tok = m0 + wm*64 + row;
            int bl = tok >> 12, w = (tok >> 4) & 255, f = tok & 15;
            int d  = wn*64 + c8;
            size_t gaddr = ((size_t)((bl*16 + f)*8 + hh) << 15) + (size_t)w*128 + d;
            *(uint4*)(dst + gaddr) = val;
        }
    }
}

// ---------------------------------------------------------------------------
// temporal attention, flash MFMA v6.  Block = (bl,f,h,it) SINGLE 64-row
// i-pass (4096 blocks; it in bits 3-4 so 4 sharers of a K/V slice stay on
// one XCD).  K/V tile for jt+1 is register-prefetched while computing jt
// (loads overlap S/softmax/PV).  exp2 softmax.  No launch_bounds cap.
// ---------------------------------------------------------------------------
__global__ __launch_bounds__(256) void tattn_mfma(
    const bf16* __restrict__ q, const bf16* __restrict__ k, const bf16* __restrict__ v,
    bf16* __restrict__ o)
{
    __shared__ __align__(16) unsigned short Ks[64*136];    // 17,408 B  (Os overlay)
    __shared__ __align__(16) unsigned short VsT[128*72];   // 18,432 B  V^T swizzled
    __shared__ __align__(16) unsigned short Ps[4][16][72]; //  9,216 B
    unsigned short* Os = Ks;
    unsigned int* VsTdw = (unsigned int*)VsT;

    int bx = blockIdx.x;
    int hh = bx & 7, it = (bx>>3) & 3, f = (bx>>5) & 15, bl = bx >> 9;
    int i0 = it*64;
    int tid = threadIdx.x;
    int lane = tid & 63, wave = tid >> 6;
    int quad = lane >> 4, l16 = lane & 15;

    size_t baseQ = ((size_t)(bl*WW)*FF + f)*1024 + (size_t)hh*128;   // token-major
    size_t baseK = (size_t)((bl*16 + f)*8 + hh) << 15;               // [w][d] contiguous

    // Q fragments (one pass only)
    bf16x8 af[4];
    {
        size_t qa = baseQ + (size_t)(i0 + wave*16 + l16)*16384;
        #pragma unroll
        for (int kt = 0; kt < 4; kt++)
            af[kt] = *(const bf16x8*)(q + qa + kt*32 + quad*8);
    }

    f32x4 oacc[8];
    #pragma unroll
    for (int t = 0; t < 8; t++) oacc[t] = 0.f;
    float m_run[4], l_run[4];
    #pragma unroll
    for (int r = 0; r < 4; r++) { m_run[r] = -1e30f; l_run[r] = 0.f; }

    // decode for staging lanes
    int krow = tid >> 4, kc8 = (tid & 15)*8;        // K: 4 chunks of 16 rows
    int vj2 = tid & 31, vc2 = (tid >> 5)*8;         // V: pair loads

    // prologue: prefetch tile 0 into registers
    uint4 kld[4]; uint4 vla[2], vlb[2];
    #pragma unroll
    for (int p4 = 0; p4 < 4; p4++)
        kld[p4] = *(const uint4*)(k + baseK + (size_t)(p4*16 + krow)*128 + kc8);
    #pragma unroll
    for (int p = 0; p < 2; p++) {
        int j2 = vj2, c2 = p*128 + vc2;             // c2 spans 0..120 / 128..248? no:
        // V pair-load decode: lin = p*256+tid -> j2 = lin&31, c2 = (lin>>5)*8
        j2 = (p*256 + tid) & 31; c2 = ((p*256 + tid) >> 5)*8;
        vla[p] = *(const uint4*)(v + baseK + (size_t)(2*j2)*128 + c2);
        vlb[p] = *(const uint4*)(v + baseK + (size_t)(2*j2 + 1)*128 + c2);
    }

    #pragma unroll 1
    for (int jt = 0; jt < 4; jt++) {
        __syncthreads();   // prior Ks/VsT consumers done
        // store prefetched K tile
        #pragma unroll
        for (int p4 = 0; p4 < 4; p4++)
            *(uint4*)&Ks[(p4*16 + krow)*136 + kc8] = kld[p4];
        // store prefetched V^T tile (pair-packed dwords, rotation swizzle)
        #pragma unroll
        for (int p = 0; p < 2; p++) {
            int j2 = (p*256 + tid) & 31, c2 = ((p*256 + tid) >> 5)*8;
            union { uint4 u; unsigned short sh[8]; } a, b;
            a.u = vla[p]; b.u = vlb[p];
            int col2 = (((2*j2) + (c2 & 56)) & 63) >> 1;
            #pragma unroll
            for (int e = 0; e < 8; e++)
                VsTdw[(c2+e)*36 + col2] = (unsigned int)a.sh[e] | ((unsigned int)b.sh[e] << 16);
        }
        // prefetch next tile (overlaps with compute below)
        if (jt < 3) {
            int jn = jt + 1;
            #pragma unroll
            for (int p4 = 0; p4 < 4; p4++)
                kld[p4] = *(const uint4*)(k + baseK + (size_t)(jn*64 + p4*16 + krow)*128 + kc8);
            #pragma unroll
            for (int p = 0; p < 2; p++) {
                int j2 = (p*256 + tid) & 31, c2 = ((p*256 + tid) >> 5)*8;
                vla[p] = *(const uint4*)(v + baseK + (size_t)(jn*64 + 2*j2)*128 + c2);
                vlb[p] = *(const uint4*)(v + baseK + (size_t)(jn*64 + 2*j2 + 1)*128 + c2);
            }
        }
        __syncthreads();

        // S tile = Q K^T, K frags from LDS
        f32x4 st[4];
        #pragma unroll
        for (int t = 0; t < 4; t++) st[t] = 0.f;
        #pragma unroll
        for (int t = 0; t < 4; t++) {
            #pragma unroll
            for (int kt = 0; kt < 4; kt++) {
                bf16x8 kf = *(const bf16x8*)&Ks[(t*16 + l16)*136 + kt*32 + quad*8];
                st[t] = MFMA16(af[kt], kf, st[t], 0, 0, 0);
            }
        }

        // online softmax (exp2 domain)
        float tmax[4];
        #pragma unroll
        for (int r = 0; r < 4; r++) tmax[r] = fmaxf(fmaxf(st[0][r], st[1][r]), fmaxf(st[2][r], st[3][r]));
        #pragma unroll
        for (int m = 1; m < 16; m <<= 1)
            #pragma unroll
            for (int r = 0; r < 4; r++) tmax[r] = fmaxf(tmax[r], __shfl_xor(tmax[r], m, 64));
        float alpha[4], rsum[4];
        #pragma unroll
        for (int r = 0; r < 4; r++) {
            float mnew = fmaxf(m_run[r], tmax[r]);
            alpha[r] = exp2f(m_run[r] - mnew);
            m_run[r] = mnew;
            rsum[r] = 0.f;
        }
        #pragma unroll
        for (int t = 0; t < 4; t++)
            #pragma unroll
            for (int r = 0; r < 4; r++) {
                float pp = exp2f(st[t][r] - m_run[r]);
                st[t][r] = pp;
                rsum[r] += pp;
            }
        #pragma unroll
        for (int m = 1; m < 16; m <<= 1)
            #pragma unroll
            for (int r = 0; r < 4; r++) rsum[r] += __shfl_xor(rsum[r], m, 64);
        #pragma unroll
        for (int r = 0; r < 4; r++) l_run[r] = l_run[r]*alpha[r] + rsum[r];
        #pragma unroll
        for (int t = 0; t < 8; t++)
            #pragma unroll
            for (int r = 0; r < 4; r++) oacc[t][r] *= alpha[r];

        // P -> per-wave LDS
        #pragma unroll
        for (int t = 0; t < 4; t++)
            #pragma unroll
            for (int r = 0; r < 4; r++)
                Ps[wave][quad*4+r][t*16+l16] = bfbits(st[t][r]);

        // PV
        #pragma unroll
        for (int kt2 = 0; kt2 < 2; kt2++) {
            int kbase = kt2*32 + quad*8;
            bf16x8 pf = *(const bf16x8*)&Ps[wave][l16][kbase];
            #pragma unroll
            for (int t = 0; t < 8; t++) {
                int d = t*16 + l16;
                int colstart = (kbase + (((d>>3)&7) << 3)) & 63;
                bf16x8 vf = *(const bf16x8*)&VsT[d*72 + colstart];
                oacc[t] = MFMA16(pf, vf, oacc[t], 0, 0, 0);
            }
        }
    }

    // epilogue: normalize, stage to Os overlay (on Ks), coalesced store
    __syncthreads();
    float inv[4];
    #pragma unroll
    for (int r = 0; r < 4; r++) inv[r] = 1.f / l_run[r];
    #pragma unroll
    for (int t = 0; t < 8; t++)
        #pragma unroll
        for (int r = 0; r < 4; r++)
            Os[(wave*16 + quad*4 + r)*136 + t*16 + l16] = bfbits(oacc[t][r]*inv[r]);
    __syncthreads();
    #pragma unroll
    for (int r4 = 0; r4 < 4; r4++) {
        int row = r4*4 + quad;
        uint4 val = *(const uint4*)&Os[(wave*16 + row)*136 + l16*8];
        size_t gaddr = baseQ + (size_t)(i0 + wave*16 + row)*16384 + l16*8;
        *(uint4*)(o + gaddr) = val;
    }
}

// ---------------------------------------------------------------------------
// FUSED vattn + out-proj + residual + (optional) LN.  One block per (bl,w).
// q/k QK fragments hoisted to kernel top (complete during staging barrier).
// ---------------------------------------------------------------------------
__global__ __launch_bounds__(256) void vproj_mfma(
    const bf16* __restrict__ q, const bf16* __restrict__ k, const bf16* __restrict__ v,
    const bf16* __restrict__ ot, const bf16* __restrict__ woT,
    const float* __restrict__ bo, float* __restrict__ h,
    bf16* __restrict__ hn, const float* __restrict__ gN, const float* __restrict__ bN,
    int donorm, int tokbase)
{
    __shared__ __align__(16) unsigned short VsT[16768];     // 33,536 B
    __shared__ __align__(16) unsigned short Ps[4][16][24];  //  3,072 B
    __shared__ float red2[4][16][2];                        //    512 B
    unsigned short* Osum = VsT;
    unsigned int* VsTdw = (unsigned int*)VsT;

    int tid = threadIdx.x;
    int lane = tid & 63, wave = tid >> 6, quad = lane >> 4, l16 = lane & 15;
    int bl = blockIdx.x >> 8, w = blockIdx.x & 255;
    size_t base = (size_t)blockIdx.x * 16384;
    size_t woff = (size_t)w * 128;

    // hoisted QK fragment loads for both heads (complete during staging)
    bf16x8 qpre[2][4], kpre[2][4];
    #pragma unroll
    for (int hi = 0; hi < 2; hi++) {
        int hh = wave*2 + hi;
        size_t hb = base + hh*128 + (size_t)l16*1024;
        size_t ka = (((size_t)((bl*16 + l16)*8 + hh)) << 15) + woff;
        #pragma unroll
        for (int kt = 0; kt < 4; kt++) {
            qpre[hi][kt] = *(const bf16x8*)(q + hb + kt*32 + quad*8);
            kpre[hi][kt] = *(const bf16x8*)(k + ka + kt*32 + quad*8);
        }
    }

    // prefetch ot
    uint4 otpre[8];
    #pragma unroll
    for (int u = 0; u < 8; u++) {
        int lin = u*256 + tid;
        int fr = lin >> 7, dc = (lin & 127)*8;
        otpre[u] = *(const uint4*)(ot + base + (size_t)fr*1024 + dc);
    }

    // stage V^T: [col=h*128+d][f], stride 16; pair-packed b32 stores
    #pragma unroll
    for (int p = 0; p < 4; p++) {
        int lin = p*256 + tid;
        int j2 = lin & 7;
        int d0 = (lin >> 3)*8;
        int hh2 = d0 >> 7, dd = d0 & 127;
        union { uint4 u; unsigned short sh[8]; } a, b;
        a.u = *(const uint4*)(v + (((size_t)((bl*16 + 2*j2  )*8 + hh2)) << 15) + woff + dd);
        b.u = *(const uint4*)(v + (((size_t)((bl*16 + 2*j2+1)*8 + hh2)) << 15) + woff + dd);
        #pragma unroll
        for (int e = 0; e < 8; e++)
            VsTdw[(d0+e)*8 + j2] = (unsigned int)a.sh[e] | ((unsigned int)b.sh[e] << 16);
    }
    __syncthreads();

    bf16x8 zf = {0,0,0,0,0,0,0,0};
    f32x4 oa[2][8];
    #pragma unroll
    for (int hi = 0; hi < 2; hi++) {
        int hh = wave*2 + hi;

        f32x4 s = {0.f,0.f,0.f,0.f};
        #pragma unroll
        for (int kt = 0; kt < 4; kt++)
            s = MFMA16(qpre[hi][kt], kpre[hi][kt], s, 0, 0, 0);
        float p[4];
        #pragma unroll
        for (int r = 0; r < 4; r++) {
            float mxv = s[r];
            #pragma unroll
            for (int m = 1; m < 16; m <<= 1) mxv = fmaxf(mxv, __shfl_xor(mxv, m, 64));
            float e = exp2f(s[r] - mxv);
            float smv = e;
            #pragma unroll
            for (int m = 1; m < 16; m <<= 1) smv += __shfl_xor(smv, m, 64);
            p[r] = e / smv;
        }
        #pragma unroll
        for (int r = 0; r < 4; r++) Ps[wave][quad*4+r][l16] = bfbits(p[r]);

        bf16x8 pf = zf;
        if (quad < 2) pf = *(const bf16x8*)&Ps[wave][l16][quad*8];
        #pragma unroll
        for (int dt = 0; dt < 8; dt++) oa[hi][dt] = 0.f;
        #pragma unroll
        for (int dt = 0; dt < 8; dt++) {
            bf16x8 vf = zf;
            if (quad < 2) vf = *(const bf16x8*)&VsT[(size_t)(hh*128 + dt*16 + l16)*16 + quad*8];
            oa[hi][dt] = MFMA16(pf, vf, oa[hi][dt], 0, 0, 0);
        }
    }

    // stage ov into Osum overlay
    __syncthreads();
    #pragma unroll
    for (int hi = 0; hi < 2; hi++) {
        int hh = wave*2 + hi;
        #pragma unroll
        for (int dt = 0; dt < 8; dt++)
            #pragma unroll
            for (int r = 0; r < 4; r++)
                Osum[(quad*4 + r)*1048 + hh*128 + dt*16 + l16] = bfbits(oa[hi][dt][r]);
    }
    __syncthreads();

    // osum += ot
    #pragma unroll
    for (int u = 0; u < 8; u++) {
        int lin = u*256 + tid;
        int fr = lin >> 7, dc = (lin & 127)*8;
        union { uint4 u4; unsigned short sh[8]; } a, bsh, wv;
        a.u4   = otpre[u];
        bsh.u4 = *(const uint4*)&Osum[fr*1048 + dc];
        #pragma unroll
        for (int e = 0; e < 8; e++)
            wv.sh[e] = bfbits(bits2f(a.sh[e]) + bits2f(bsh.sh[e]));
        *(uint4*)&Osum[fr*1048 + dc] = wv.u4;
    }
    __syncthreads();

    // proj
    f32x4 pacc[2];
    pacc[0] = 0.f; pacc[1] = 0.f;
    #pragma unroll 4
    for (int kt2 = 0; kt2 < 32; kt2++) {
        bf16x8 af2 = *(const bf16x8*)&Osum[l16*1048 + kt2*32 + quad*8];
        #pragma unroll
        for (int nt = 0; nt < 2; nt++) {
            bf16x8 bfr = *(const bf16x8*)(woT + (size_t)(wave*32 + nt*16 + l16)*1024 + kt2*32 + quad*8);
            pacc[nt] = MFMA16(af2, bfr, pacc[nt], 0, 0, 0);
        }
    }

    // epilogue: residual; optional LN -> hn
    int htok = tokbase + blockIdx.x*16;
    float hv[2][4];
    #pragma unroll
    for (int nt = 0; nt < 2; nt++) {
        int n = wave*32 + nt*16 + l16;
        float bias = bo[n];
        #pragma unroll
        for (int r = 0; r < 4; r++) {
            size_t idx = (size_t)(htok + quad*4 + r)*128 + n;
            float nv = h[idx] + pacc[nt][r] + bias;
            h[idx] = nv;
            hv[nt][r] = nv;
        }
    }

    if (donorm) {
        float s1[4], s2[4];
        #pragma unroll
        for (int r = 0; r < 4; r++) {
            s1[r] = hv[0][r] + hv[1][r];
            s2[r] = hv[0][r]*hv[0][r] + hv[1][r]*hv[1][r];
        }
        #pragma unroll
        for (int m = 1; m < 16; m <<= 1)
            #pragma unroll
            for (int r = 0; r < 4; r++) {
                s1[r] += __shfl_xor(s1[r], m, 64);
                s2[r] += __shfl_xor(s2[r], m, 64);
            }
        __syncthreads();
        if (l16 == 0) {
            #pragma unroll
            for (int r = 0; r < 4; r++) {
                red2[wave][quad*4+r][0] = s1[r];
                red2[wave][quad*4+r][1] = s2[r];
            }
        }
        __syncthreads();
        #pragma unroll
        for (int nt = 0; nt < 2; nt++) {
            int n = wave*32 + nt*16 + l16;
            float gn = gN[n], bn = bN[n];
            #pragma unroll
            for (int r = 0; r < 4; r++) {
                int t = quad*4 + r;
                float t1 = red2[0][t][0] + red2[1][t][0] + red2[2][t][0] + red2[3][t][0];
                float t2 = red2[0][t][1] + red2[1][t][1] + red2[2][t][1] + red2[3][t][1];
                float mean = t1*INV_D;
                float var  = t2*INV_D - mean*mean;
                float rsv = rsqrtf(var + 1e-5f);
                Osum[t*1048 + n] = bfbits((hv[nt][r]-mean)*rsv*gn + bn);
            }
        }
        __syncthreads();
        int row = tid >> 4, c8 = (tid & 15)*8;
        uint4 val = *(const uint4*)&Osum[row*1048 + c8];
        *(uint4*)(hn + (size_t)(htok + row)*128 + c8) = val;
    }
}

// ---------------------------------------------------------------------------
// head, MFMA: out[2048,16] = h[2048,2048]@whT^T + bh
// ---------------------------------------------------------------------------
__global__ __launch_bounds__(256) void head_mfma(
    const float* __restrict__ h, const bf16* __restrict__ whT,
    const float* __restrict__ bh, float* __restrict__ out)
{
    __shared__ float sred[4][16][17];
    int tid = threadIdx.x;
    int lane = tid & 63, wave = tid >> 6, quad = lane >> 4, l16 = lane & 15;
    int bw0 = blockIdx.x * 16;
    const float* hrow = h + (size_t)(bw0 + l16)*2048 + wave*512;
    const bf16* wrow  = whT + (size_t)l16*2048 + wave*512;

    f32x4 acc = {0.f,0.f,0.f,0.f};
    #pragma unroll 4
    for (int kc = 0; kc < 16; kc++) {
        int ko = kc*32 + quad*8;
        float4 a0 = *(const float4*)(hrow + ko);
        float4 a1 = *(const float4*)(hrow + ko + 4);
        union { bf16x8 v; unsigned short sh[8]; } ua;
        ua.sh[0]=bfbits(a0.x); ua.sh[1]=bfbits(a0.y); ua.sh[2]=bfbits(a0.z); ua.sh[3]=bfbits(a0.w);
        ua.sh[4]=bfbits(a1.x); ua.sh[5]=bfbits(a1.y); ua.sh[6]=bfbits(a1.z); ua.sh[7]=bfbits(a1.w);
        bf16x8 bv = *(const bf16x8*)(wrow + ko);
        acc = MFMA16(ua.v, bv, acc, 0, 0, 0);
    }
    #pragma unroll
    for (int r = 0; r < 4; r++) sred[wave][quad*4+r][l16] = acc[r];
    __syncthreads();
    int i = tid >> 4, n = tid & 15;
    float s = bh[n] + sred[0][i][n] + sred[1][i][n] + sred[2][i][n] + sred[3][i][n];
    out[(size_t)(bw0 + i)*16 + n] = s;
}

// ---------------------------------------------------------------------------
extern "C" void kernel_launch(void* const* d_in, const int* in_sizes, int n_in,
                              void* d_out, int out_size, void* d_ws, size_t ws_size,
                              hipStream_t stream)
{
    const float* x    = (const float*)d_in[0];
    const float* w1   = (const float*)d_in[1];
    const float* b1   = (const float*)d_in[2];
    const float* w2   = (const float*)d_in[3];
    const float* b2   = (const float*)d_in[4];
    const float* w3   = (const float*)d_in[5];
    const float* b3   = (const float*)d_in[6];
    const float* wval = (const float*)d_in[7];
    const float* bval = (const float*)d_in[8];
    const float* lng  = (const float*)d_in[9];
    const float* lnb  = (const float*)d_in[10];
    const float* wqkv = (const float*)d_in[11];
    const float* wout = (const float*)d_in[12];
    const float* bout = (const float*)d_in[13];
    const float* wh   = (const float*)d_in[14];
    const float* bh   = (const float*)d_in[15];
    float* out = (float*)d_out;

    char* ws = (char*)d_ws;
    bf16*  wqkvT = (bf16*)ws;                       // 3,145,728 B
    bf16*  woutT = (bf16*)(ws + 3145728);           // 1,048,576 B
    bf16*  whT   = (bf16*)(ws + 4194304);           //    65,536 B
    float* h     = (float*)(ws + 4259840);          // 16,777,216 B
    bf16*  hn    = (bf16*)(ws + 21037056);          //  8,388,608 B
    const size_t qoff = 29425664ull;

    int NBL = 1;
    if      (ws_size >= qoff + 8ull*4ull*8388608ull) NBL = 8;
    else if (ws_size >= qoff + 4ull*4ull*8388608ull) NBL = 4;
    else if (ws_size >= qoff + 2ull*4ull*8388608ull) NBL = 2;
    size_t bsz = (size_t)NBL * 8388608ull;
    bf16* q  = (bf16*)(ws + qoff);
    bf16* kk = (bf16*)(ws + qoff + bsz);
    bf16* vv = (bf16*)(ws + qoff + 2*bsz);
    bf16* oo = (bf16*)(ws + qoff + 3*bsz);

    prep_kernel<<<544 + BB*WW, 256, 0, stream>>>(
        wqkv, wout, wh, wqkvT, woutT, whT,
        x, w1,b1, w2,b2, w3,b3, wval, bval, lng, lnb, h, hn);

    for (int l = 0; l < 4; l++) {
        const bf16* wqT_l = wqkvT + (size_t)l*3072*128;
        const bf16* woT_l = woutT + (size_t)l*128*1024;
        const float* bo_l = bout + l*128;
        int donorm = (l < 3) ? 1 : 0;
        const float* gN = lng + (donorm ? (l+1)*128 : 0);
        const float* bN = lnb + (donorm ? (l+1)*128 : 0);
        for (int bb = 0; bb < BB; bb += NBL) {
            int tokbase = bb*WW*FF;
            qkv_mfma<<<dim3(NBL*32, 24), 256, 0, stream>>>(
                hn + (size_t)tokbase*128, wqT_l, q, kk, vv);
            tattn_mfma<<<NBL*FF*HH*4, 256, 0, stream>>>(q, kk, vv, oo);
            vproj_mfma<<<NBL*WW, 256, 0, stream>>>(q, kk, vv, oo, woT_l,
                                                   bo_l, h, hn, gN, bN,
                                                   donorm, tokbase);
        }
    }

    head_mfma<<<BB*WW/16, 256, 0, stream>>>(h, whT, bh, out);
}

// Round 13
// 1410.917 us; speedup vs baseline: 1.0602x; 1.0602x over previous
//
#include <hip/hip_runtime.h>
#include <hip/hip_bf16.h>
#include <math.h>

#define BB 8
#define WW 256
#define FF 16
#define DD 128
#define HH 8
#define NTOK (BB*WW*FF)        // 32768
#define QSCALE 0.12751745f     // DH^-0.5 * log2(e)  (softmax uses exp2)
#define INV_D (1.0f/128.0f)
#define LN10K_D 0.07195578415606394f   // ln(10000)/128

typedef __hip_bfloat16 bf16;
typedef short bf16x8 __attribute__((ext_vector_type(8)));   // 8 bf16 = 4 VGPRs
typedef float f32x4 __attribute__((ext_vector_type(4)));

__device__ __forceinline__ float bf2f(bf16 x){ return __bfloat162float(x); }
__device__ __forceinline__ bf16 f2bf(float x){ return __float2bfloat16(x); }
__device__ __forceinline__ unsigned short bfbits(float x){ bf16 b = f2bf(x); return *(unsigned short*)&b; }
__device__ __forceinline__ float bits2f(unsigned short u){ bf16 b = *(bf16*)&u; return __bfloat162float(b); }

#define MFMA16 __builtin_amdgcn_mfma_f32_16x16x32_bf16

// k/v layout: [bl][f][h][w][d] (w,d contiguous per (b,f,h): 64 KB slice).
// q/ot: token-major [tok][h*128+d].

// ---------------------------------------------------------------------------
// MERGED prep: blocks 0..543 = weight transpose+convert; 544.. = embed(+LN0).
// ---------------------------------------------------------------------------
__global__ __launch_bounds__(256) void prep_kernel(
    const float* __restrict__ wqkv, const float* __restrict__ wout,
    const float* __restrict__ wh,
    bf16* __restrict__ wqkvT, bf16* __restrict__ woutT, bf16* __restrict__ whT,
    const float* __restrict__ x,
    const float* __restrict__ w1, const float* __restrict__ b1,
    const float* __restrict__ w2, const float* __restrict__ b2,
    const float* __restrict__ w3, const float* __restrict__ b3,
    const float* __restrict__ wval, const float* __restrict__ bval,
    const float* __restrict__ g, const float* __restrict__ bln,
    float* __restrict__ h, bf16* __restrict__ hn)
{
    __shared__ __align__(16) char smem[16640];
    int tid = threadIdx.x;

    if (blockIdx.x < 544) {
        float (*tile)[65] = (float(*)[65])smem;
        int bx = blockIdx.x;
        const float* in; bf16* outp; int r0, c0, sin, sout, nmax;
        if (bx < 384) {
            int l = bx / 96, t = bx % 96;
            r0 = (t / 48)*64; c0 = (t % 48)*64;
            in = wqkv + (size_t)l*128*3072; outp = wqkvT + (size_t)l*3072*128;
            sin = 3072; sout = 128; nmax = 3072;
        } else if (bx < 512) {
            int j = bx - 384, l = j / 32, t = j % 32;
            r0 = (t / 2)*64; c0 = (t % 2)*64;
            in = wout + (size_t)l*1024*128; outp = woutT + (size_t)l*128*1024;
            sin = 128; sout = 1024; nmax = 128;
        } else {
            int t = bx - 512;
            r0 = t*64; c0 = 0;
            in = wh; outp = whT; sin = 16; sout = 2048; nmax = 16;
        }
        int rr = tid >> 2, cg = (tid & 3)*16;
        if (c0 + cg < nmax) {
            const float* src = in + (size_t)(r0 + rr)*sin + c0 + cg;
            #pragma unroll
            for (int i = 0; i < 4; i++)
                *(float4*)&tile[rr][cg + i*4] = *(const float4*)(src + i*4);
        }
        __syncthreads();
        int n = c0 + rr;
        if (n < nmax) {
            union { uint4 u[2]; unsigned short sh[16]; } o;
            #pragma unroll
            for (int e = 0; e < 16; e++) o.sh[e] = bfbits(tile[cg + e][rr]);
            bf16* dst = outp + (size_t)n*sout + r0 + cg;
            *(uint4*)dst = o.u[0];
            *(uint4*)(dst + 8) = o.u[1];
        }
        return;
    }

    float (*s)[4] = (float(*)[4])smem;
    float* hs = (float*)(smem + 256);
    int bw = blockIdx.x - 544;
    int b = bw >> 8, w = bw & 255;
    if (tid < 64) {
        int f = tid >> 2, t = tid & 3;
        const float* xb = x + (size_t)b*WW*FF + f;
        float v;
        if (t == 0) {
            v = xb[(size_t)w*FF];
        } else if (t == 1) {
            float acc = b1[f];
            #pragma unroll
            for (int kk = 0; kk < 4; kk++) { int t0 = w - (3-kk); if (t0 >= 0) acc += w1[f*4+kk]*xb[(size_t)t0*FF]; }
            v = acc;
        } else if (t == 2) {
            float acc = b2[f];
            #pragma unroll
            for (int kk = 0; kk < 8; kk++) { int t0 = w - (7-kk)*2; if (t0 >= 0) acc += w2[f*8+kk]*xb[(size_t)t0*FF]; }
            v = acc;
        } else {
            float acc = b3[f];
            #pragma unroll
            for (int kk = 0; kk < 16; kk++) { int t0 = w - (15-kk)*3; if (t0 >= 0) acc += w3[f*16+kk]*xb[(size_t)t0*FF]; }
            v = acc;
        }
        s[f][t] = v;
    }
    __syncthreads();
    #pragma unroll
    for (int r = 0; r < 8; r++) {
        int lin = r*256 + tid;
        int f = lin >> 7, d = lin & 127;
        float div = expf(-(float)(d & ~1) * LN10K_D);
        float arg = (float)w * div;
        float pe = (d & 1) ? cosf(arg) : sinf(arg);
        float e = bval[d] + pe;
        #pragma unroll
        for (int t = 0; t < 4; t++) e += s[f][t]*wval[t*128 + d];
        h[((size_t)bw*FF + f)*128 + d] = e;
        hs[f*132 + d] = e;
    }
    __syncthreads();
    int tok = tid >> 4, sub = tid & 15;
    float xv[8];
    #pragma unroll
    for (int e2 = 0; e2 < 8; e2++) xv[e2] = hs[tok*132 + sub*8 + e2];
    float s1 = 0.f, s2 = 0.f;
    #pragma unroll
    for (int e2 = 0; e2 < 8; e2++) { s1 += xv[e2]; s2 += xv[e2]*xv[e2]; }
    #pragma unroll
    for (int m = 1; m < 16; m <<= 1) { s1 += __shfl_xor(s1, m, 64); s2 += __shfl_xor(s2, m, 64); }
    float mean = s1*INV_D;
    float var  = s2*INV_D - mean*mean;
    float rs = rsqrtf(var + 1e-5f);
    union { uint4 u; unsigned short sh[8]; } ou;
    #pragma unroll
    for (int e2 = 0; e2 < 8; e2++) {
        int d = sub*8 + e2;
        ou.sh[e2] = bfbits((xv[e2]-mean)*rs*g[d] + bln[d]);
    }
    *(uint4*)(hn + ((size_t)bw*16 + tok)*128 + sub*8) = ou.u;
}

// ---------------------------------------------------------------------------
// QKV GEMM, MFMA.  q -> token-major (scaled by QSCALE); k/v -> [bl][f][h][w][d].
// ---------------------------------------------------------------------------
__global__ __launch_bounds__(256) void qkv_mfma(
    const bf16* __restrict__ hn, const bf16* __restrict__ wT,
    bf16* __restrict__ q, bf16* __restrict__ k, bf16* __restrict__ v)
{
    __shared__ __align__(16) unsigned short Cs[4][64][72];   // 36,864 B
    int tid = threadIdx.x;
    int lane = tid & 63, wave = tid >> 6;
    int quad = lane >> 4, l16 = lane & 15;
    int wm = wave >> 1, wn = wave & 1;
    int m0 = blockIdx.x * 128, n0 = blockIdx.y * 128;

    f32x4 acc[4][4];
    #pragma unroll
    for (int a = 0; a < 4; a++)
        #pragma unroll
        for (int c = 0; c < 4; c++) acc[a][c] = 0.f;

    #pragma unroll
    for (int kt = 0; kt < 4; kt++) {
        int ko = kt*32 + quad*8;
        bf16x8 af[4], bfr[4];
        #pragma unroll
        for (int tm = 0; tm < 4; tm++)
            af[tm] = *(const bf16x8*)(hn + (size_t)(m0 + wm*64 + tm*16 + l16)*128 + ko);
        #pragma unroll
        for (int tn = 0; tn < 4; tn++)
            bfr[tn] = *(const bf16x8*)(wT + (size_t)(n0 + wn*64 + tn*16 + l16)*128 + ko);
        #pragma unroll
        for (int tm = 0; tm < 4; tm++)
            #pragma unroll
            for (int tn = 0; tn < 4; tn++)
                acc[tm][tn] = MFMA16(af[tm], bfr[tn], acc[tm][tn], 0, 0, 0);
    }

    bf16* dst; int nrel; float scl; int isq;
    if (n0 < 1024)      { dst = q; nrel = n0;        scl = QSCALE; isq = 1; }
    else if (n0 < 2048) { dst = k; nrel = n0 - 1024; scl = 1.0f;   isq = 0; }
    else                { dst = v; nrel = n0 - 2048; scl = 1.0f;   isq = 0; }

    #pragma unroll
    for (int tm = 0; tm < 4; tm++)
        #pragma unroll
        for (int tn = 0; tn < 4; tn++)
            #pragma unroll
            for (int r = 0; r < 4; r++)
                Cs[wave][tm*16 + quad*4 + r][tn*16 + l16] = bfbits(acc[tm][tn][r]*scl);

    if (isq) {
        #pragma unroll
        for (int p = 0; p < 8; p++) {
            int row = p*8 + (lane >> 3);
            int c8  = (lane & 7)*8;
            uint4 val = *(const uint4*)&Cs[wave][row][c8];
            size_t gaddr = (size_t)(m0 + wm*64 + row)*1024 + nrel + wn*64 + c8;
            *(uint4*)(dst + gaddr) = val;
        }
    } else {
        int hh = nrel >> 7;
        #pragma unroll
        for (int p = 0; p < 8; p++) {
            int row = p*8 + (lane >> 3);
            int c8  = (lane & 7)*8;
            uint4 val = *(const uint4*)&Cs[wave][row][c8];
            int tok = m0 + wm*64 + row;
            int bl = tok >> 12, w = (tok >> 4) & 255, f = tok & 15;
            int d  = wn*64 + c8;
            size_t gaddr = ((size_t)((bl*16 + f)*8 + hh) << 15) + (size_t)w*128 + d;
            *(uint4*)(dst + gaddr) = val;
        }
    }
}

// ---------------------------------------------------------------------------
// temporal attention, flash MFMA v7.  Block = (bl,f,h,it) single 64-row
// i-pass (4096 blocks; it in bits 3-4 -> 4 sharers of one K/V slice stay on
// one XCD).  Demand-staged K+V tiles into LDS per jt (no register prefetch
// across barriers -- spill lesson of rounds 6/10/12).  exp2 softmax.
// ---------------------------------------------------------------------------
__global__ __launch_bounds__(256) void tattn_mfma(
    const bf16* __restrict__ q, const bf16* __restrict__ k, const bf16* __restrict__ v,
    bf16* __restrict__ o)
{
    __shared__ __align__(16) unsigned short Ks[64*136];    // 17,408 B  (Os overlay)
    __shared__ __align__(16) unsigned short VsT[128*72];   // 18,432 B  V^T swizzled
    __shared__ __align__(16) unsigned short Ps[4][16][72]; //  9,216 B
    unsigned short* Os = Ks;
    unsigned int* VsTdw = (unsigned int*)VsT;

    int bx = blockIdx.x;
    int hh = bx & 7, it = (bx>>3) & 3, f = (bx>>5) & 15, bl = bx >> 9;
    int i0 = it*64;
    int tid = threadIdx.x;
    int lane = tid & 63, wave = tid >> 6;
    int quad = lane >> 4, l16 = lane & 15;

    size_t baseQ = ((size_t)(bl*WW)*FF + f)*1024 + (size_t)hh*128;   // token-major
    size_t baseK = (size_t)((bl*16 + f)*8 + hh) << 15;               // [w][d] contiguous

    // Q fragments
    bf16x8 af[4];
    {
        size_t qa = baseQ + (size_t)(i0 + wave*16 + l16)*16384;
        #pragma unroll
        for (int kt = 0; kt < 4; kt++)
            af[kt] = *(const bf16x8*)(q + qa + kt*32 + quad*8);
    }

    f32x4 oacc[8];
    #pragma unroll
    for (int t = 0; t < 8; t++) oacc[t] = 0.f;
    float m_run[4], l_run[4];
    #pragma unroll
    for (int r = 0; r < 4; r++) { m_run[r] = -1e30f; l_run[r] = 0.f; }

    int krow = tid >> 4, kc8 = (tid & 15)*8;

    #pragma unroll 1
    for (int jt = 0; jt < 4; jt++) {
        __syncthreads();   // prior Ks/VsT consumers done
        // co-op stage K tile [64][128] -> Ks (stride 136), uint4 both sides
        #pragma unroll
        for (int p4 = 0; p4 < 4; p4++)
            *(uint4*)&Ks[(p4*16 + krow)*136 + kc8] =
                *(const uint4*)(k + baseK + (size_t)(jt*64 + p4*16 + krow)*128 + kc8);
        // co-op stage V^T tile: pair-packed b32 stores, rotation swizzle
        #pragma unroll
        for (int p = 0; p < 2; p++) {
            int lin = p*256 + tid;
            int j2 = lin & 31, c2 = (lin >> 5)*8;
            union { uint4 u; unsigned short sh[8]; } a, b;
            a.u = *(const uint4*)(v + baseK + (size_t)(jt*64 + 2*j2)*128 + c2);
            b.u = *(const uint4*)(v + baseK + (size_t)(jt*64 + 2*j2 + 1)*128 + c2);
            int col2 = (((2*j2) + (c2 & 56)) & 63) >> 1;
            #pragma unroll
            for (int e = 0; e < 8; e++)
                VsTdw[(c2+e)*36 + col2] = (unsigned int)a.sh[e] | ((unsigned int)b.sh[e] << 16);
        }
        __syncthreads();

        // S tile = Q K^T, K frags from LDS (ds_read_b128)
        f32x4 st[4];
        #pragma unroll
        for (int t = 0; t < 4; t++) st[t] = 0.f;
        #pragma unroll
        for (int t = 0; t < 4; t++) {
            #pragma unroll
            for (int kt = 0; kt < 4; kt++) {
                bf16x8 kf = *(const bf16x8*)&Ks[(t*16 + l16)*136 + kt*32 + quad*8];
                st[t] = MFMA16(af[kt], kf, st[t], 0, 0, 0);
            }
        }

        // online softmax (exp2 domain)
        float tmax[4];
        #pragma unroll
        for (int r = 0; r < 4; r++) tmax[r] = fmaxf(fmaxf(st[0][r], st[1][r]), fmaxf(st[2][r], st[3][r]));
        #pragma unroll
        for (int m = 1; m < 16; m <<= 1)
            #pragma unroll
            for (int r = 0; r < 4; r++) tmax[r] = fmaxf(tmax[r], __shfl_xor(tmax[r], m, 64));
        float alpha[4], rsum[4];
        #pragma unroll
        for (int r = 0; r < 4; r++) {
            float mnew = fmaxf(m_run[r], tmax[r]);
            alpha[r] = exp2f(m_run[r] - mnew);
            m_run[r] = mnew;
            rsum[r] = 0.f;
        }
        #pragma unroll
        for (int t = 0; t < 4; t++)
            #pragma unroll
            for (int r = 0; r < 4; r++) {
                float pp = exp2f(st[t][r] - m_run[r]);
                st[t][r] = pp;
                rsum[r] += pp;
            }
        #pragma unroll
        for (int m = 1; m < 16; m <<= 1)
            #pragma unroll
            for (int r = 0; r < 4; r++) rsum[r] += __shfl_xor(rsum[r], m, 64);
        #pragma unroll
        for (int r = 0; r < 4; r++) l_run[r] = l_run[r]*alpha[r] + rsum[r];
        #pragma unroll
        for (int t = 0; t < 8; t++)
            #pragma unroll
            for (int r = 0; r < 4; r++) oacc[t][r] *= alpha[r];

        // P -> per-wave LDS
        #pragma unroll
        for (int t = 0; t < 4; t++)
            #pragma unroll
            for (int r = 0; r < 4; r++)
                Ps[wave][quad*4+r][t*16+l16] = bfbits(st[t][r]);

        // PV
        #pragma unroll
        for (int kt2 = 0; kt2 < 2; kt2++) {
            int kbase = kt2*32 + quad*8;
            bf16x8 pf = *(const bf16x8*)&Ps[wave][l16][kbase];
            #pragma unroll
            for (int t = 0; t < 8; t++) {
                int d = t*16 + l16;
                int colstart = (kbase + (((d>>3)&7) << 3)) & 63;
                bf16x8 vf = *(const bf16x8*)&VsT[d*72 + colstart];
                oacc[t] = MFMA16(pf, vf, oacc[t], 0, 0, 0);
            }
        }
    }

    // epilogue: normalize, stage to Os overlay (on Ks), coalesced store
    __syncthreads();
    float inv[4];
    #pragma unroll
    for (int r = 0; r < 4; r++) inv[r] = 1.f / l_run[r];
    #pragma unroll
    for (int t = 0; t < 8; t++)
        #pragma unroll
        for (int r = 0; r < 4; r++)
            Os[(wave*16 + quad*4 + r)*136 + t*16 + l16] = bfbits(oacc[t][r]*inv[r]);
    __syncthreads();
    #pragma unroll
    for (int r4 = 0; r4 < 4; r4++) {
        int row = r4*4 + quad;
        uint4 val = *(const uint4*)&Os[(wave*16 + row)*136 + l16*8];
        size_t gaddr = baseQ + (size_t)(i0 + wave*16 + row)*16384 + l16*8;
        *(uint4*)(o + gaddr) = val;
    }
}

// ---------------------------------------------------------------------------
// FUSED vattn + out-proj + residual + (optional) LN.  One block per (bl,w).
// q/k QK fragments hoisted to kernel top (complete during staging barrier).
// ---------------------------------------------------------------------------
__global__ __launch_bounds__(256) void vproj_mfma(
    const bf16* __restrict__ q, const bf16* __restrict__ k, const bf16* __restrict__ v,
    const bf16* __restrict__ ot, const bf16* __restrict__ woT,
    const float* __restrict__ bo, float* __restrict__ h,
    bf16* __restrict__ hn, const float* __restrict__ gN, const float* __restrict__ bN,
    int donorm, int tokbase)
{
    __shared__ __align__(16) unsigned short VsT[16768];     // 33,536 B
    __shared__ __align__(16) unsigned short Ps[4][16][24];  //  3,072 B
    __shared__ float red2[4][16][2];                        //    512 B
    unsigned short* Osum = VsT;
    unsigned int* VsTdw = (unsigned int*)VsT;

    int tid = threadIdx.x;
    int lane = tid & 63, wave = tid >> 6, quad = lane >> 4, l16 = lane & 15;
    int bl = blockIdx.x >> 8, w = blockIdx.x & 255;
    size_t base = (size_t)blockIdx.x * 16384;
    size_t woff = (size_t)w * 128;

    // hoisted QK fragment loads for both heads (complete during staging)
    bf16x8 qpre[2][4], kpre[2][4];
    #pragma unroll
    for (int hi = 0; hi < 2; hi++) {
        int hh = wave*2 + hi;
        size_t hb = base + hh*128 + (size_t)l16*1024;
        size_t ka = (((size_t)((bl*16 + l16)*8 + hh)) << 15) + woff;
        #pragma unroll
        for (int kt = 0; kt < 4; kt++) {
            qpre[hi][kt] = *(const bf16x8*)(q + hb + kt*32 + quad*8);
            kpre[hi][kt] = *(const bf16x8*)(k + ka + kt*32 + quad*8);
        }
    }

    // prefetch ot
    uint4 otpre[8];
    #pragma unroll
    for (int u = 0; u < 8; u++) {
        int lin = u*256 + tid;
        int fr = lin >> 7, dc = (lin & 127)*8;
        otpre[u] = *(const uint4*)(ot + base + (size_t)fr*1024 + dc);
    }

    // stage V^T: [col=h*128+d][f], stride 16; pair-packed b32 stores
    #pragma unroll
    for (int p = 0; p < 4; p++) {
        int lin = p*256 + tid;
        int j2 = lin & 7;
        int d0 = (lin >> 3)*8;
        int hh2 = d0 >> 7, dd = d0 & 127;
        union { uint4 u; unsigned short sh[8]; } a, b;
        a.u = *(const uint4*)(v + (((size_t)((bl*16 + 2*j2  )*8 + hh2)) << 15) + woff + dd);
        b.u = *(const uint4*)(v + (((size_t)((bl*16 + 2*j2+1)*8 + hh2)) << 15) + woff + dd);
        #pragma unroll
        for (int e = 0; e < 8; e++)
            VsTdw[(d0+e)*8 + j2] = (unsigned int)a.sh[e] | ((unsigned int)b.sh[e] << 16);
    }
    __syncthreads();

    bf16x8 zf = {0,0,0,0,0,0,0,0};
    f32x4 oa[2][8];
    #pragma unroll
    for (int hi = 0; hi < 2; hi++) {
        int hh = wave*2 + hi;

        f32x4 s = {0.f,0.f,0.f,0.f};
        #pragma unroll
        for (int kt = 0; kt < 4; kt++)
            s = MFMA16(qpre[hi][kt], kpre[hi][kt], s, 0, 0, 0);
        float p[4];
        #pragma unroll
        for (int r = 0; r < 4; r++) {
            float mxv = s[r];
            #pragma unroll
            for (int m = 1; m < 16; m <<= 1) mxv = fmaxf(mxv, __shfl_xor(mxv, m, 64));
            float e = exp2f(s[r] - mxv);
            float smv = e;
            #pragma unroll
            for (int m = 1; m < 16; m <<= 1) smv += __shfl_xor(smv, m, 64);
            p[r] = e / smv;
        }
        #pragma unroll
        for (int r = 0; r < 4; r++) Ps[wave][quad*4+r][l16] = bfbits(p[r]);

        bf16x8 pf = zf;
        if (quad < 2) pf = *(const bf16x8*)&Ps[wave][l16][quad*8];
        #pragma unroll
        for (int dt = 0; dt < 8; dt++) oa[hi][dt] = 0.f;
        #pragma unroll
        for (int dt = 0; dt < 8; dt++) {
            bf16x8 vf = zf;
            if (quad < 2) vf = *(const bf16x8*)&VsT[(size_t)(hh*128 + dt*16 + l16)*16 + quad*8];
            oa[hi][dt] = MFMA16(pf, vf, oa[hi][dt], 0, 0, 0);
        }
    }

    // stage ov into Osum overlay
    __syncthreads();
    #pragma unroll
    for (int hi = 0; hi < 2; hi++) {
        int hh = wave*2 + hi;
        #pragma unroll
        for (int dt = 0; dt < 8; dt++)
            #pragma unroll
            for (int r = 0; r < 4; r++)
                Osum[(quad*4 + r)*1048 + hh*128 + dt*16 + l16] = bfbits(oa[hi][dt][r]);
    }
    __syncthreads();

    // osum += ot
    #pragma unroll
    for (int u = 0; u < 8; u++) {
        int lin = u*256 + tid;
        int fr = lin >> 7, dc = (lin & 127)*8;
        union { uint4 u4; unsigned short sh[8]; } a, bsh, wv;
        a.u4   = otpre[u];
        bsh.u4 = *(const uint4*)&Osum[fr*1048 + dc];
        #pragma unroll
        for (int e = 0; e < 8; e++)
            wv.sh[e] = bfbits(bits2f(a.sh[e]) + bits2f(bsh.sh[e]));
        *(uint4*)&Osum[fr*1048 + dc] = wv.u4;
    }
    __syncthreads();

    // proj
    f32x4 pacc[2];
    pacc[0] = 0.f; pacc[1] = 0.f;
    #pragma unroll 4
    for (int kt2 = 0; kt2 < 32; kt2++) {
        bf16x8 af2 = *(const bf16x8*)&Osum[l16*1048 + kt2*32 + quad*8];
        #pragma unroll
        for (int nt = 0; nt < 2; nt++) {
            bf16x8 bfr = *(const bf16x8*)(woT + (size_t)(wave*32 + nt*16 + l16)*1024 + kt2*32 + quad*8);
            pacc[nt] = MFMA16(af2, bfr, pacc[nt], 0, 0, 0);
        }
    }

    // epilogue: residual; optional LN -> hn
    int htok = tokbase + blockIdx.x*16;
    float hv[2][4];
    #pragma unroll
    for (int nt = 0; nt < 2; nt++) {
        int n = wave*32 + nt*16 + l16;
        float bias = bo[n];
        #pragma unroll
        for (int r = 0; r < 4; r++) {
            size_t idx = (size_t)(htok + quad*4 + r)*128 + n;
            float nv = h[idx] + pacc[nt][r] + bias;
            h[idx] = nv;
            hv[nt][r] = nv;
        }
    }

    if (donorm) {
        float s1[4], s2[4];
        #pragma unroll
        for (int r = 0; r < 4; r++) {
            s1[r] = hv[0][r] + hv[1][r];
            s2[r] = hv[0][r]*hv[0][r] + hv[1][r]*hv[1][r];
        }
        #pragma unroll
        for (int m = 1; m < 16; m <<= 1)
            #pragma unroll
            for (int r = 0; r < 4; r++) {
                s1[r] += __shfl_xor(s1[r], m, 64);
                s2[r] += __shfl_xor(s2[r], m, 64);
            }
        __syncthreads();
        if (l16 == 0) {
            #pragma unroll
            for (int r = 0; r < 4; r++) {
                red2[wave][quad*4+r][0] = s1[r];
                red2[wave][quad*4+r][1] = s2[r];
            }
        }
        __syncthreads();
        #pragma unroll
        for (int nt = 0; nt < 2; nt++) {
            int n = wave*32 + nt*16 + l16;
            float gn = gN[n], bn = bN[n];
            #pragma unroll
            for (int r = 0; r < 4; r++) {
                int t = quad*4 + r;
                float t1 = red2[0][t][0] + red2[1][t][0] + red2[2][t][0] + red2[3][t][0];
                float t2 = red2[0][t][1] + red2[1][t][1] + red2[2][t][1] + red2[3][t][1];
                float mean = t1*INV_D;
                float var  = t2*INV_D - mean*mean;
                float rsv = rsqrtf(var + 1e-5f);
                Osum[t*1048 + n] = bfbits((hv[nt][r]-mean)*rsv*gn + bn);
            }
        }
        __syncthreads();
        int row = tid >> 4, c8 = (tid & 15)*8;
        uint4 val = *(const uint4*)&Osum[row*1048 + c8];
        *(uint4*)(hn + (size_t)(htok + row)*128 + c8) = val;
    }
}

// ---------------------------------------------------------------------------
// head, MFMA: out[2048,16] = h[2048,2048]@whT^T + bh
// ---------------------------------------------------------------------------
__global__ __launch_bounds__(256) void head_mfma(
    const float* __restrict__ h, const bf16* __restrict__ whT,
    const float* __restrict__ bh, float* __restrict__ out)
{
    __shared__ float sred[4][16][17];
    int tid = threadIdx.x;
    int lane = tid & 63, wave = tid >> 6, quad = lane >> 4, l16 = lane & 15;
    int bw0 = blockIdx.x * 16;
    const float* hrow = h + (size_t)(bw0 + l16)*2048 + wave*512;
    const bf16* wrow  = whT + (size_t)l16*2048 + wave*512;

    f32x4 acc = {0.f,0.f,0.f,0.f};
    #pragma unroll 4
    for (int kc = 0; kc < 16; kc++) {
        int ko = kc*32 + quad*8;
        float4 a0 = *(const float4*)(hrow + ko);
        float4 a1 = *(const float4*)(hrow + ko + 4);
        union { bf16x8 v; unsigned short sh[8]; } ua;
        ua.sh[0]=bfbits(a0.x); ua.sh[1]=bfbits(a0.y); ua.sh[2]=bfbits(a0.z); ua.sh[3]=bfbits(a0.w);
        ua.sh[4]=bfbits(a1.x); ua.sh[5]=bfbits(a1.y); ua.sh[6]=bfbits(a1.z); ua.sh[7]=bfbits(a1.w);
        bf16x8 bv = *(const bf16x8*)(wrow + ko);
        acc = MFMA16(ua.v, bv, acc, 0, 0, 0);
    }
    #pragma unroll
    for (int r = 0; r < 4; r++) sred[wave][quad*4+r][l16] = acc[r];
    __syncthreads();
    int i = tid >> 4, n = tid & 15;
    float s = bh[n] + sred[0][i][n] + sred[1][i][n] + sred[2][i][n] + sred[3][i][n];
    out[(size_t)(bw0 + i)*16 + n] = s;
}

// ---------------------------------------------------------------------------
extern "C" void kernel_launch(void* const* d_in, const int* in_sizes, int n_in,
                              void* d_out, int out_size, void* d_ws, size_t ws_size,
                              hipStream_t stream)
{
    const float* x    = (const float*)d_in[0];
    const float* w1   = (const float*)d_in[1];
    const float* b1   = (const float*)d_in[2];
    const float* w2   = (const float*)d_in[3];
    const float* b2   = (const float*)d_in[4];
    const float* w3   = (const float*)d_in[5];
    const float* b3   = (const float*)d_in[6];
    const float* wval = (const float*)d_in[7];
    const float* bval = (const float*)d_in[8];
    const float* lng  = (const float*)d_in[9];
    const float* lnb  = (const float*)d_in[10];
    const float* wqkv = (const float*)d_in[11];
    const float* wout = (const float*)d_in[12];
    const float* bout = (const float*)d_in[13];
    const float* wh   = (const float*)d_in[14];
    const float* bh   = (const float*)d_in[15];
    float* out = (float*)d_out;

    char* ws = (char*)d_ws;
    bf16*  wqkvT = (bf16*)ws;                       // 3,145,728 B
    bf16*  woutT = (bf16*)(ws + 3145728);           // 1,048,576 B
    bf16*  whT   = (bf16*)(ws + 4194304);           //    65,536 B
    float* h     = (float*)(ws + 4259840);          // 16,777,216 B
    bf16*  hn    = (bf16*)(ws + 21037056);          //  8,388,608 B
    const size_t qoff = 29425664ull;

    int NBL = 1;
    if      (ws_size >= qoff + 8ull*4ull*8388608ull) NBL = 8;
    else if (ws_size >= qoff + 4ull*4ull*8388608ull) NBL = 4;
    else if (ws_size >= qoff + 2ull*4ull*8388608ull) NBL = 2;
    size_t bsz = (size_t)NBL * 8388608ull;
    bf16* q  = (bf16*)(ws + qoff);
    bf16* kk = (bf16*)(ws + qoff + bsz);
    bf16* vv = (bf16*)(ws + qoff + 2*bsz);
    bf16* oo = (bf16*)(ws + qoff + 3*bsz);

    prep_kernel<<<544 + BB*WW, 256, 0, stream>>>(
        wqkv, wout, wh, wqkvT, woutT, whT,
        x, w1,b1, w2,b2, w3,b3, wval, bval, lng, lnb, h, hn);

    for (int l = 0; l < 4; l++) {
        const bf16* wqT_l = wqkvT + (size_t)l*3072*128;
        const bf16* woT_l = woutT + (size_t)l*128*1024;
        const float* bo_l = bout + l*128;
        int donorm = (l < 3) ? 1 : 0;
        const float* gN = lng + (donorm ? (l+1)*128 : 0);
        const float* bN = lnb + (donorm ? (l+1)*128 : 0);
        for (int bb = 0; bb < BB; bb += NBL) {
            int tokbase = bb*WW*FF;
            qkv_mfma<<<dim3(NBL*32, 24), 256, 0, stream>>>(
                hn + (size_t)tokbase*128, wqT_l, q, kk, vv);
            tattn_mfma<<<NBL*FF*HH*4, 256, 0, stream>>>(q, kk, vv, oo);
            vproj_mfma<<<NBL*WW, 256, 0, stream>>>(q, kk, vv, oo, woT_l,
                                                   bo_l, h, hn, gN, bN,
                                                   donorm, tokbase);
        }
    }

    head_mfma<<<BB*WW/16, 256, 0, stream>>>(h, whT, bh, out);
}

// Round 15
// 1399.061 us; speedup vs baseline: 1.0692x; 1.0085x over previous
//
#include <hip/hip_runtime.h>
#include <hip/hip_bf16.h>
#include <math.h>

#define BB 8
#define WW 256
#define FF 16
#define DD 128
#define HH 8
#define NTOK (BB*WW*FF)        // 32768
#define QSCALE 0.12751745f     // DH^-0.5 * log2(e)  (softmax uses exp2)
#define INV_D (1.0f/128.0f)
#define LN10K_D 0.07195578415606394f   // ln(10000)/128

typedef __hip_bfloat16 bf16;
typedef short bf16x8 __attribute__((ext_vector_type(8)));   // 8 bf16 = 4 VGPRs
typedef float f32x4 __attribute__((ext_vector_type(4)));

__device__ __forceinline__ float bf2f(bf16 x){ return __bfloat162float(x); }
__device__ __forceinline__ bf16 f2bf(float x){ return __float2bfloat16(x); }
__device__ __forceinline__ unsigned short bfbits(float x){ bf16 b = f2bf(x); return *(unsigned short*)&b; }
__device__ __forceinline__ float bits2f(unsigned short u){ bf16 b = *(bf16*)&u; return __bfloat162float(b); }

#define MFMA16 __builtin_amdgcn_mfma_f32_16x16x32_bf16

// k/v layout: [bl][f][h][w][d] (w,d contiguous per (b,f,h): 64 KB slice).
// q/ot: token-major [tok][h*128+d].

// ---------------------------------------------------------------------------
// MERGED prep: blocks 0..543 = weight transpose+convert; 544.. = embed(+LN0).
// ---------------------------------------------------------------------------
__global__ __launch_bounds__(256) void prep_kernel(
    const float* __restrict__ wqkv, const float* __restrict__ wout,
    const float* __restrict__ wh,
    bf16* __restrict__ wqkvT, bf16* __restrict__ woutT, bf16* __restrict__ whT,
    const float* __restrict__ x,
    const float* __restrict__ w1, const float* __restrict__ b1,
    const float* __restrict__ w2, const float* __restrict__ b2,
    const float* __restrict__ w3, const float* __restrict__ b3,
    const float* __restrict__ wval, const float* __restrict__ bval,
    const float* __restrict__ g, const float* __restrict__ bln,
    float* __restrict__ h, bf16* __restrict__ hn)
{
    __shared__ __align__(16) char smem[16640];
    int tid = threadIdx.x;

    if (blockIdx.x < 544) {
        float (*tile)[65] = (float(*)[65])smem;
        int bx = blockIdx.x;
        const float* in; bf16* outp; int r0, c0, sin, sout, nmax;
        if (bx < 384) {
            int l = bx / 96, t = bx % 96;
            r0 = (t / 48)*64; c0 = (t % 48)*64;
            in = wqkv + (size_t)l*128*3072; outp = wqkvT + (size_t)l*3072*128;
            sin = 3072; sout = 128; nmax = 3072;
        } else if (bx < 512) {
            int j = bx - 384, l = j / 32, t = j % 32;
            r0 = (t / 2)*64; c0 = (t % 2)*64;
            in = wout + (size_t)l*1024*128; outp = woutT + (size_t)l*128*1024;
            sin = 128; sout = 1024; nmax = 128;
        } else {
            int t = bx - 512;
            r0 = t*64; c0 = 0;
            in = wh; outp = whT; sin = 16; sout = 2048; nmax = 16;
        }
        int rr = tid >> 2, cg = (tid & 3)*16;
        if (c0 + cg < nmax) {
            const float* src = in + (size_t)(r0 + rr)*sin + c0 + cg;
            #pragma unroll
            for (int i = 0; i < 4; i++)
                *(float4*)&tile[rr][cg + i*4] = *(const float4*)(src + i*4);
        }
        __syncthreads();
        int n = c0 + rr;
        if (n < nmax) {
            union { uint4 u[2]; unsigned short sh[16]; } o;
            #pragma unroll
            for (int e = 0; e < 16; e++) o.sh[e] = bfbits(tile[cg + e][rr]);
            bf16* dst = outp + (size_t)n*sout + r0 + cg;
            *(uint4*)dst = o.u[0];
            *(uint4*)(dst + 8) = o.u[1];
        }
        return;
    }

    float (*s)[4] = (float(*)[4])smem;
    float* hs = (float*)(smem + 256);
    int bw = blockIdx.x - 544;
    int b = bw >> 8, w = bw & 255;
    if (tid < 64) {
        int f = tid >> 2, t = tid & 3;
        const float* xb = x + (size_t)b*WW*FF + f;
        float v;
        if (t == 0) {
            v = xb[(size_t)w*FF];
        } else if (t == 1) {
            float acc = b1[f];
            #pragma unroll
            for (int kk = 0; kk < 4; kk++) { int t0 = w - (3-kk); if (t0 >= 0) acc += w1[f*4+kk]*xb[(size_t)t0*FF]; }
            v = acc;
        } else if (t == 2) {
            float acc = b2[f];
            #pragma unroll
            for (int kk = 0; kk < 8; kk++) { int t0 = w - (7-kk)*2; if (t0 >= 0) acc += w2[f*8+kk]*xb[(size_t)t0*FF]; }
            v = acc;
        } else {
            float acc = b3[f];
            #pragma unroll
            for (int kk = 0; kk < 16; kk++) { int t0 = w - (15-kk)*3; if (t0 >= 0) acc += w3[f*16+kk]*xb[(size_t)t0*FF]; }
            v = acc;
        }
        s[f][t] = v;
    }
    __syncthreads();
    #pragma unroll
    for (int r = 0; r < 8; r++) {
        int lin = r*256 + tid;
        int f = lin >> 7, d = lin & 127;
        float div = expf(-(float)(d & ~1) * LN10K_D);
        float arg = (float)w * div;
        float pe = (d & 1) ? cosf(arg) : sinf(arg);
        float e = bval[d] + pe;
        #pragma unroll
        for (int t = 0; t < 4; t++) e += s[f][t]*wval[t*128 + d];
        h[((size_t)bw*FF + f)*128 + d] = e;
        hs[f*132 + d] = e;
    }
    __syncthreads();
    int tok = tid >> 4, sub = tid & 15;
    float xv[8];
    #pragma unroll
    for (int e2 = 0; e2 < 8; e2++) xv[e2] = hs[tok*132 + sub*8 + e2];
    float s1 = 0.f, s2 = 0.f;
    #pragma unroll
    for (int e2 = 0; e2 < 8; e2++) { s1 += xv[e2]; s2 += xv[e2]*xv[e2]; }
    #pragma unroll
    for (int m = 1; m < 16; m <<= 1) { s1 += __shfl_xor(s1, m, 64); s2 += __shfl_xor(s2, m, 64); }
    float mean = s1*INV_D;
    float var  = s2*INV_D - mean*mean;
    float rs = rsqrtf(var + 1e-5f);
    union { uint4 u; unsigned short sh[8]; } ou;
    #pragma unroll
    for (int e2 = 0; e2 < 8; e2++) {
        int d = sub*8 + e2;
        ou.sh[e2] = bfbits((xv[e2]-mean)*rs*g[d] + bln[d]);
    }
    *(uint4*)(hn + ((size_t)bw*16 + tok)*128 + sub*8) = ou.u;
}

// ---------------------------------------------------------------------------
// QKV GEMM, MFMA.  q -> token-major (scaled by QSCALE); k/v -> [bl][f][h][w][d].
// ---------------------------------------------------------------------------
__global__ __launch_bounds__(256) void qkv_mfma(
    const bf16* __restrict__ hn, const bf16* __restrict__ wT,
    bf16* __restrict__ q, bf16* __restrict__ k, bf16* __restrict__ v)
{
    __shared__ __align__(16) unsigned short Cs[4][64][72];   // 36,864 B
    int tid = threadIdx.x;
    int lane = tid & 63, wave = tid >> 6;
    int quad = lane >> 4, l16 = lane & 15;
    int wm = wave >> 1, wn = wave & 1;
    int m0 = blockIdx.x * 128, n0 = blockIdx.y * 128;

    f32x4 acc[4][4];
    #pragma unroll
    for (int a = 0; a < 4; a++)
        #pragma unroll
        for (int c = 0; c < 4; c++) acc[a][c] = 0.f;

    #pragma unroll
    for (int kt = 0; kt < 4; kt++) {
        int ko = kt*32 + quad*8;
        bf16x8 af[4], bfr[4];
        #pragma unroll
        for (int tm = 0; tm < 4; tm++)
            af[tm] = *(const bf16x8*)(hn + (size_t)(m0 + wm*64 + tm*16 + l16)*128 + ko);
        #pragma unroll
        for (int tn = 0; tn < 4; tn++)
            bfr[tn] = *(const bf16x8*)(wT + (size_t)(n0 + wn*64 + tn*16 + l16)*128 + ko);
        #pragma unroll
        for (int tm = 0; tm < 4; tm++)
            #pragma unroll
            for (int tn = 0; tn < 4; tn++)
                acc[tm][tn] = MFMA16(af[tm], bfr[tn], acc[tm][tn], 0, 0, 0);
    }

    bf16* dst; int nrel; float scl; int isq;
    if (n0 < 1024)      { dst = q; nrel = n0;        scl = QSCALE; isq = 1; }
    else if (n0 < 2048) { dst = k; nrel = n0 - 1024; scl = 1.0f;   isq = 0; }
    else                { dst = v; nrel = n0 - 2048; scl = 1.0f;   isq = 0; }

    #pragma unroll
    for (int tm = 0; tm < 4; tm++)
        #pragma unroll
        for (int tn = 0; tn < 4; tn++)
            #pragma unroll
            for (int r = 0; r < 4; r++)
                Cs[wave][tm*16 + quad*4 + r][tn*16 + l16] = bfbits(acc[tm][tn][r]*scl);

    if (isq) {
        #pragma unroll
        for (int p = 0; p < 8; p++) {
            int row = p*8 + (lane >> 3);
            int c8  = (lane & 7)*8;
            uint4 val = *(const uint4*)&Cs[wave][row][c8];
            size_t gaddr = (size_t)(m0 + wm*64 + row)*1024 + nrel + wn*64 + c8;
            *(uint4*)(dst + gaddr) = val;
        }
    } else {
        int hh = nrel >> 7;
        #pragma unroll
        for (int p = 0; p < 8; p++) {
            int row = p*8 + (lane >> 3);
            int c8  = (lane & 7)*8;
            uint4 val = *(const uint4*)&Cs[wave][row][c8];
            int tok = m0 + wm*64 + row;
            int bl = tok >> 12, w = (tok >> 4) & 255, f = tok & 15;
            int d  = wn*64 + c8;
            size_t gaddr = ((size_t)((bl*16 + f)*8 + hh) << 15) + (size_t)w*128 + d;
            *(uint4*)(dst + gaddr) = val;
        }
    }
}

// ---------------------------------------------------------------------------
// temporal attention, flash MFMA v8.  Block = (bl,f,h,it) single 64-row
// i-pass (4096 blocks; it in bits 3-4 -> 4 K/V-slice sharers on one XCD).
// Demand-staged K+V tiles in LDS.  NEW: Ps overlays the Ks region (Ks is
// dead after the S-phase MFMAs); one extra barrier after S makes it safe.
// LDS 45,056 -> 35,840 B => 4 blocks/CU (was 3).  exp2 softmax.
// ---------------------------------------------------------------------------
__global__ __launch_bounds__(256) void tattn_mfma(
    const bf16* __restrict__ q, const bf16* __restrict__ k, const bf16* __restrict__ v,
    bf16* __restrict__ o)
{
    __shared__ __align__(16) unsigned short Ks[64*136];    // 17,408 B (Ps + Os overlay)
    __shared__ __align__(16) unsigned short VsT[128*72];   // 18,432 B  V^T swizzled
    unsigned short* Os = Ks;
    unsigned int* VsTdw = (unsigned int*)VsT;

    int bx = blockIdx.x;
    int hh = bx & 7, it = (bx>>3) & 3, f = (bx>>5) & 15, bl = bx >> 9;
    int i0 = it*64;
    int tid = threadIdx.x;
    int lane = tid & 63, wave = tid >> 6;
    int quad = lane >> 4, l16 = lane & 15;
    unsigned short* Psw = Ks + wave*1152;   // per-wave P region (16 x 72), on Ks

    size_t baseQ = ((size_t)(bl*WW)*FF + f)*1024 + (size_t)hh*128;   // token-major
    size_t baseK = (size_t)((bl*16 + f)*8 + hh) << 15;               // [w][d] contiguous

    // Q fragments
    bf16x8 af[4];
    {
        size_t qa = baseQ + (size_t)(i0 + wave*16 + l16)*16384;
        #pragma unroll
        for (int kt = 0; kt < 4; kt++)
            af[kt] = *(const bf16x8*)(q + qa + kt*32 + quad*8);
    }

    f32x4 oacc[8];
    #pragma unroll
    for (int t = 0; t < 8; t++) oacc[t] = 0.f;
    float m_run[4], l_run[4];
    #pragma unroll
    for (int r = 0; r < 4; r++) { m_run[r] = -1e30f; l_run[r] = 0.f; }

    int krow = tid >> 4, kc8 = (tid & 15)*8;

    #pragma unroll 1
    for (int jt = 0; jt < 4; jt++) {
        __syncthreads();   // prior Ks(P)/VsT consumers done
        // co-op stage K tile [64][128] -> Ks (stride 136), uint4 both sides
        #pragma unroll
        for (int p4 = 0; p4 < 4; p4++)
            *(uint4*)&Ks[(p4*16 + krow)*136 + kc8] =
                *(const uint4*)(k + baseK + (size_t)(jt*64 + p4*16 + krow)*128 + kc8);
        // co-op stage V^T tile: pair-packed b32 stores, rotation swizzle
        #pragma unroll
        for (int p = 0; p < 2; p++) {
            int lin = p*256 + tid;
            int j2 = lin & 31, c2 = (lin >> 5)*8;
            union { uint4 u; unsigned short sh[8]; } a, b;
            a.u = *(const uint4*)(v + baseK + (size_t)(jt*64 + 2*j2)*128 + c2);
            b.u = *(const uint4*)(v + baseK + (size_t)(jt*64 + 2*j2 + 1)*128 + c2);
            int col2 = (((2*j2) + (c2 & 56)) & 63) >> 1;
            #pragma unroll
            for (int e = 0; e < 8; e++)
                VsTdw[(c2+e)*36 + col2] = (unsigned int)a.sh[e] | ((unsigned int)b.sh[e] << 16);
        }
        __syncthreads();

        // S tile = Q K^T, K frags from LDS (ds_read_b128)
        f32x4 st[4];
        #pragma unroll
        for (int t = 0; t < 4; t++) st[t] = 0.f;
        #pragma unroll
        for (int t = 0; t < 4; t++) {
            #pragma unroll
            for (int kt = 0; kt < 4; kt++) {
                bf16x8 kf = *(const bf16x8*)&Ks[(t*16 + l16)*136 + kt*32 + quad*8];
                st[t] = MFMA16(af[kt], kf, st[t], 0, 0, 0);
            }
        }
        __syncthreads();   // all waves done reading Ks -> P may overlay it

        // online softmax (exp2 domain)
        float tmax[4];
        #pragma unroll
        for (int r = 0; r < 4; r++) tmax[r] = fmaxf(fmaxf(st[0][r], st[1][r]), fmaxf(st[2][r], st[3][r]));
        #pragma unroll
        for (int m = 1; m < 16; m <<= 1)
            #pragma unroll
            for (int r = 0; r < 4; r++) tmax[r] = fmaxf(tmax[r], __shfl_xor(tmax[r], m, 64));
        float alpha[4], rsum[4];
        #pragma unroll
        for (int r = 0; r < 4; r++) {
            float mnew = fmaxf(m_run[r], tmax[r]);
            alpha[r] = exp2f(m_run[r] - mnew);
            m_run[r] = mnew;
            rsum[r] = 0.f;
        }
        #pragma unroll
        for (int t = 0; t < 4; t++)
            #pragma unroll
            for (int r = 0; r < 4; r++) {
                float pp = exp2f(st[t][r] - m_run[r]);
                st[t][r] = pp;
                rsum[r] += pp;
            }
        #pragma unroll
        for (int m = 1; m < 16; m <<= 1)
            #pragma unroll
            for (int r = 0; r < 4; r++) rsum[r] += __shfl_xor(rsum[r], m, 64);
        #pragma unroll
        for (int r = 0; r < 4; r++) l_run[r] = l_run[r]*alpha[r] + rsum[r];
        #pragma unroll
        for (int t = 0; t < 8; t++)
            #pragma unroll
            for (int r = 0; r < 4; r++) oacc[t][r] *= alpha[r];

        // P -> per-wave region on Ks (wave-private; lgkmcnt orders wr->rd)
        #pragma unroll
        for (int t = 0; t < 4; t++)
            #pragma unroll
            for (int r = 0; r < 4; r++)
                Psw[(quad*4+r)*72 + t*16+l16] = bfbits(st[t][r]);

        // PV
        #pragma unroll
        for (int kt2 = 0; kt2 < 2; kt2++) {
            int kbase = kt2*32 + quad*8;
            bf16x8 pf = *(const bf16x8*)&Psw[l16*72 + kbase];
            #pragma unroll
            for (int t = 0; t < 8; t++) {
                int d = t*16 + l16;
                int colstart = (kbase + (((d>>3)&7) << 3)) & 63;
                bf16x8 vf = *(const bf16x8*)&VsT[d*72 + colstart];
                oacc[t] = MFMA16(pf, vf, oacc[t], 0, 0, 0);
            }
        }
    }

    // epilogue: normalize, stage to Os overlay (on Ks), coalesced store
    __syncthreads();
    float inv[4];
    #pragma unroll
    for (int r = 0; r < 4; r++) inv[r] = 1.f / l_run[r];
    #pragma unroll
    for (int t = 0; t < 8; t++)
        #pragma unroll
        for (int r = 0; r < 4; r++)
            Os[(wave*16 + quad*4 + r)*136 + t*16 + l16] = bfbits(oacc[t][r]*inv[r]);
    __syncthreads();
    #pragma unroll
    for (int r4 = 0; r4 < 4; r4++) {
        int row = r4*4 + quad;
        uint4 val = *(const uint4*)&Os[(wave*16 + row)*136 + l16*8];
        size_t gaddr = baseQ + (size_t)(i0 + wave*16 + row)*16384 + l16*8;
        *(uint4*)(o + gaddr) = val;
    }
}

// ---------------------------------------------------------------------------
// FUSED vattn + out-proj + residual + (optional) LN.  One block per (bl,w).
// q/k QK fragments hoisted to kernel top (complete during staging barrier).
// ---------------------------------------------------------------------------
__global__ __launch_bounds__(256) void vproj_mfma(
    const bf16* __restrict__ q, const bf16* __restrict__ k, const bf16* __restrict__ v,
    const bf16* __restrict__ ot, const bf16* __restrict__ woT,
    const float* __restrict__ bo, float* __restrict__ h,
    bf16* __restrict__ hn, const float* __restrict__ gN, const float* __restrict__ bN,
    int donorm, int tokbase)
{
    __shared__ __align__(16) unsigned short VsT[16768];     // 33,536 B
    __shared__ __align__(16) unsigned short Ps[4][16][24];  //  3,072 B
    __shared__ float red2[4][16][2];                        //    512 B
    unsigned short* Osum = VsT;
    unsigned int* VsTdw = (unsigned int*)VsT;

    int tid = threadIdx.x;
    int lane = tid & 63, wave = tid >> 6, quad = lane >> 4, l16 = lane & 15;
    int bl = blockIdx.x >> 8, w = blockIdx.x & 255;
    size_t base = (size_t)blockIdx.x * 16384;
    size_t woff = (size_t)w * 128;

    // hoisted QK fragment loads for both heads (complete during staging)
    bf16x8 qpre[2][4], kpre[2][4];
    #pragma unroll
    for (int hi = 0; hi < 2; hi++) {
        int hh = wave*2 + hi;
        size_t hb = base + hh*128 + (size_t)l16*1024;
        size_t ka = (((size_t)((bl*16 + l16)*8 + hh)) << 15) + woff;
        #pragma unroll
        for (int kt = 0; kt < 4; kt++) {
            qpre[hi][kt] = *(const bf16x8*)(q + hb + kt*32 + quad*8);
            kpre[hi][kt] = *(const bf16x8*)(k + ka + kt*32 + quad*8);
        }
    }

    // prefetch ot
    uint4 otpre[8];
    #pragma unroll
    for (int u = 0; u < 8; u++) {
        int lin = u*256 + tid;
        int fr = lin >> 7, dc = (lin & 127)*8;
        otpre[u] = *(const uint4*)(ot + base + (size_t)fr*1024 + dc);
    }

    // stage V^T: [col=h*128+d][f], stride 16; pair-packed b32 stores
    #pragma unroll
    for (int p = 0; p < 4; p++) {
        int lin = p*256 + tid;
        int j2 = lin & 7;
        int d0 = (lin >> 3)*8;
        int hh2 = d0 >> 7, dd = d0 & 127;
        union { uint4 u; unsigned short sh[8]; } a, b;
        a.u = *(const uint4*)(v + (((size_t)((bl*16 + 2*j2  )*8 + hh2)) << 15) + woff + dd);
        b.u = *(const uint4*)(v + (((size_t)((bl*16 + 2*j2+1)*8 + hh2)) << 15) + woff + dd);
        #pragma unroll
        for (int e = 0; e < 8; e++)
            VsTdw[(d0+e)*8 + j2] = (unsigned int)a.sh[e] | ((unsigned int)b.sh[e] << 16);
    }
    __syncthreads();

    bf16x8 zf = {0,0,0,0,0,0,0,0};
    f32x4 oa[2][8];
    #pragma unroll
    for (int hi = 0; hi < 2; hi++) {
        int hh = wave*2 + hi;

        f32x4 s = {0.f,0.f,0.f,0.f};
        #pragma unroll
        for (int kt = 0; kt < 4; kt++)
            s = MFMA16(qpre[hi][kt], kpre[hi][kt], s, 0, 0, 0);
        float p[4];
        #pragma unroll
        for (int r = 0; r < 4; r++) {
            float mxv = s[r];
            #pragma unroll
            for (int m = 1; m < 16; m <<= 1) mxv = fmaxf(mxv, __shfl_xor(mxv, m, 64));
            float e = exp2f(s[r] - mxv);
            float smv = e;
            #pragma unroll
            for (int m = 1; m < 16; m <<= 1) smv += __shfl_xor(smv, m, 64);
            p[r] = e / smv;
        }
        #pragma unroll
        for (int r = 0; r < 4; r++) Ps[wave][quad*4+r][l16] = bfbits(p[r]);

        bf16x8 pf = zf;
        if (quad < 2) pf = *(const bf16x8*)&Ps[wave][l16][quad*8];
        #pragma unroll
        for (int dt = 0; dt < 8; dt++) oa[hi][dt] = 0.f;
        #pragma unroll
        for (int dt = 0; dt < 8; dt++) {
            bf16x8 vf = zf;
            if (quad < 2) vf = *(const bf16x8*)&VsT[(size_t)(hh*128 + dt*16 + l16)*16 + quad*8];
            oa[hi][dt] = MFMA16(pf, vf, oa[hi][dt], 0, 0, 0);
        }
    }

    // stage ov into Osum overlay
    __syncthreads();
    #pragma unroll
    for (int hi = 0; hi < 2; hi++) {
        int hh = wave*2 + hi;
        #pragma unroll
        for (int dt = 0; dt < 8; dt++)
            #pragma unroll
            for (int r = 0; r < 4; r++)
                Osum[(quad*4 + r)*1048 + hh*128 + dt*16 + l16] = bfbits(oa[hi][dt][r]);
    }
    __syncthreads();

    // osum += ot
    #pragma unroll
    for (int u = 0; u < 8; u++) {
        int lin = u*256 + tid;
        int fr = lin >> 7, dc = (lin & 127)*8;
        union { uint4 u4; unsigned short sh[8]; } a, bsh, wv;
        a.u4   = otpre[u];
        bsh.u4 = *(const uint4*)&Osum[fr*1048 + dc];
        #pragma unroll
        for (int e = 0; e < 8; e++)
            wv.sh[e] = bfbits(bits2f(a.sh[e]) + bits2f(bsh.sh[e]));
        *(uint4*)&Osum[fr*1048 + dc] = wv.u4;
    }
    __syncthreads();

    // proj
    f32x4 pacc[2];
    pacc[0] = 0.f; pacc[1] = 0.f;
    #pragma unroll 4
    for (int kt2 = 0; kt2 < 32; kt2++) {
        bf16x8 af2 = *(const bf16x8*)&Osum[l16*1048 + kt2*32 + quad*8];
        #pragma unroll
        for (int nt = 0; nt < 2; nt++) {
            bf16x8 bfr = *(const bf16x8*)(woT + (size_t)(wave*32 + nt*16 + l16)*1024 + kt2*32 + quad*8);
            pacc[nt] = MFMA16(af2, bfr, pacc[nt], 0, 0, 0);
        }
    }

    // epilogue: residual; optional LN -> hn
    int htok = tokbase + blockIdx.x*16;
    float hv[2][4];
    #pragma unroll
    for (int nt = 0; nt < 2; nt++) {
        int n = wave*32 + nt*16 + l16;
        float bias = bo[n];
        #pragma unroll
        for (int r = 0; r < 4; r++) {
            size_t idx = (size_t)(htok + quad*4 + r)*128 + n;
            float nv = h[idx] + pacc[nt][r] + bias;
            h[idx] = nv;
            hv[nt][r] = nv;
        }
    }

    if (donorm) {
        float s1[4], s2[4];
        #pragma unroll
        for (int r = 0; r < 4; r++) {
            s1[r] = hv[0][r] + hv[1][r];
            s2[r] = hv[0][r]*hv[0][r] + hv[1][r]*hv[1][r];
        }
        #pragma unroll
        for (int m = 1; m < 16; m <<= 1)
            #pragma unroll
            for (int r = 0; r < 4; r++) {
                s1[r] += __shfl_xor(s1[r], m, 64);
                s2[r] += __shfl_xor(s2[r], m, 64);
            }
        __syncthreads();
        if (l16 == 0) {
            #pragma unroll
            for (int r = 0; r < 4; r++) {
                red2[wave][quad*4+r][0] = s1[r];
                red2[wave][quad*4+r][1] = s2[r];
            }
        }
        __syncthreads();
        #pragma unroll
        for (int nt = 0; nt < 2; nt++) {
            int n = wave*32 + nt*16 + l16;
            float gn = gN[n], bn = bN[n];
            #pragma unroll
            for (int r = 0; r < 4; r++) {
                int t = quad*4 + r;
                float t1 = red2[0][t][0] + red2[1][t][0] + red2[2][t][0] + red2[3][t][0];
                float t2 = red2[0][t][1] + red2[1][t][1] + red2[2][t][1] + red2[3][t][1];
                float mean = t1*INV_D;
                float var  = t2*INV_D - mean*mean;
                float rsv = rsqrtf(var + 1e-5f);
                Osum[t*1048 + n] = bfbits((hv[nt][r]-mean)*rsv*gn + bn);
            }
        }
        __syncthreads();
        int row = tid >> 4, c8 = (tid & 15)*8;
        uint4 val = *(const uint4*)&Osum[row*1048 + c8];
        *(uint4*)(hn + (size_t)(htok + row)*128 + c8) = val;
    }
}

// ---------------------------------------------------------------------------
// head, MFMA: out[2048,16] = h[2048,2048]@whT^T + bh
// ---------------------------------------------------------------------------
__global__ __launch_bounds__(256) void head_mfma(
    const float* __restrict__ h, const bf16* __restrict__ whT,
    const float* __restrict__ bh, float* __restrict__ out)
{
    __shared__ float sred[4][16][17];
    int tid = threadIdx.x;
    int lane = tid & 63, wave = tid >> 6, quad = lane >> 4, l16 = lane & 15;
    int bw0 = blockIdx.x * 16;
    const float* hrow = h + (size_t)(bw0 + l16)*2048 + wave*512;
    const bf16* wrow  = whT + (size_t)l16*2048 + wave*512;

    f32x4 acc = {0.f,0.f,0.f,0.f};
    #pragma unroll 4
    for (int kc = 0; kc < 16; kc++) {
        int ko = kc*32 + quad*8;
        float4 a0 = *(const float4*)(hrow + ko);
        float4 a1 = *(const float4*)(hrow + ko + 4);
        union { bf16x8 v; unsigned short sh[8]; } ua;
        ua.sh[0]=bfbits(a0.x); ua.sh[1]=bfbits(a0.y); ua.sh[2]=bfbits(a0.z); ua.sh[3]=bfbits(a0.w);
        ua.sh[4]=bfbits(a1.x); ua.sh[5]=bfbits(a1.y); ua.sh[6]=bfbits(a1.z); ua.sh[7]=bfbits(a1.w);
        bf16x8 bv = *(const bf16x8*)(wrow + ko);
        acc = MFMA16(ua.v, bv, acc, 0, 0, 0);
    }
    #pragma unroll
    for (int r = 0; r < 4; r++) sred[wave][quad*4+r][l16] = acc[r];
    __syncthreads();
    int i = tid >> 4, n = tid & 15;
    float s = bh[n] + sred[0][i][n] + sred[1][i][n] + sred[2][i][n] + sred[3][i][n];
    out[(size_t)(bw0 + i)*16 + n] = s;
}

// ---------------------------------------------------------------------------
extern "C" void kernel_launch(void* const* d_in, const int* in_sizes, int n_in,
                              void* d_out, int out_size, void* d_ws, size_t ws_size,
                              hipStream_t stream)
{
    const float* x    = (const float*)d_in[0];
    const float* w1   = (const float*)d_in[1];
    const float* b1   = (const float*)d_in[2];
    const float* w2   = (const float*)d_in[3];
    const float* b2   = (const float*)d_in[4];
    const float* w3   = (const float*)d_in[5];
    const float* b3   = (const float*)d_in[6];
    const float* wval = (const float*)d_in[7];
    const float* bval = (const float*)d_in[8];
    const float* lng  = (const float*)d_in[9];
    const float* lnb  = (const float*)d_in[10];
    const float* wqkv = (const float*)d_in[11];
    const float* wout = (const float*)d_in[12];
    const float* bout = (const float*)d_in[13];
    const float* wh   = (const float*)d_in[14];
    const float* bh   = (const float*)d_in[15];
    float* out = (float*)d_out;

    char* ws = (char*)d_ws;
    bf16*  wqkvT = (bf16*)ws;                       // 3,145,728 B
    bf16*  woutT = (bf16*)(ws + 3145728);           // 1,048,576 B
    bf16*  whT   = (bf16*)(ws + 4194304);           //    65,536 B
    float* h     = (float*)(ws + 4259840);          // 16,777,216 B
    bf16*  hn    = (bf16*)(ws + 21037056);          //  8,388,608 B
    const size_t qoff = 29425664ull;

    int NBL = 1;
    if      (ws_size >= qoff + 8ull*4ull*8388608ull) NBL = 8;
    else if (ws_size >= qoff + 4ull*4ull*8388608ull) NBL = 4;
    else if (ws_size >= qoff + 2ull*4ull*8388608ull) NBL = 2;
    size_t bsz = (size_t)NBL * 8388608ull;
    bf16* q  = (bf16*)(ws + qoff);
    bf16* kk = (bf16*)(ws + qoff + bsz);
    bf16* vv = (bf16*)(ws + qoff + 2*bsz);
    bf16* oo = (bf16*)(ws + qoff + 3*bsz);

    prep_kernel<<<544 + BB*WW, 256, 0, stream>>>(
        wqkv, wout, wh, wqkvT, woutT, whT,
        x, w1,b1, w2,b2, w3,b3, wval, bval, lng, lnb, h, hn);

    for (int l = 0; l < 4; l++) {
        const bf16* wqT_l = wqkvT + (size_t)l*3072*128;
        const bf16* woT_l = woutT + (size_t)l*128*1024;
        const float* bo_l = bout + l*128;
        int donorm = (l < 3) ? 1 : 0;
        const float* gN = lng + (donorm ? (l+1)*128 : 0);
        const float* bN = lnb + (donorm ? (l+1)*128 : 0);
        for (int bb = 0; bb < BB; bb += NBL) {
            int tokbase = bb*WW*FF;
            qkv_mfma<<<dim3(NBL*32, 24), 256, 0, stream>>>(
                hn + (size_t)tokbase*128, wqT_l, q, kk, vv);
            tattn_mfma<<<NBL*FF*HH*4, 256, 0, stream>>>(q, kk, vv, oo);
            vproj_mfma<<<NBL*WW, 256, 0, stream>>>(q, kk, vv, oo, woT_l,
                                                   bo_l, h, hn, gN, bN,
                                                   donorm, tokbase);
        }
    }

    head_mfma<<<BB*WW/16, 256, 0, stream>>>(h, whT, bh, out);
}